// Round 1
// baseline (129.178 us; speedup 1.0000x reference)
//
#include <hip/hip_runtime.h>
#include <math.h>

// Problem constants
#define Mm 4096   // batch B
#define Nn 4096   // 4*H (gate-major: n = g*1024 + h)
#define Kk 2048   // D + H

typedef __bf16 bf16x8 __attribute__((ext_vector_type(8)));
typedef float f32x4 __attribute__((ext_vector_type(4)));

__device__ __forceinline__ unsigned short f2bf(float f) {
    union { float f; unsigned u; } v; v.f = f;
    unsigned r = v.u + 0x7FFFu + ((v.u >> 16) & 1u);  // RNE
    return (unsigned short)(r >> 16);
}
__device__ __forceinline__ float bf2f(unsigned short s) {
    union { unsigned u; float f; } v; v.u = ((unsigned)s) << 16;
    return v.f;
}

// ---------------------------------------------------------------------------
// Kernel 1: pack x|h -> Xcat bf16 [4096][2048], W|U -> Wcat bf16 [4096][2048]
// ---------------------------------------------------------------------------
__global__ void pack_bf16(const float* __restrict__ x, const float* __restrict__ h,
                          const float* __restrict__ W, const float* __restrict__ U,
                          unsigned short* __restrict__ Xc, unsigned short* __restrict__ Wc) {
    const int PER = (4096 * 1024) / 4;  // float4 chunks per region = 2^20
    for (int t = blockIdx.x * blockDim.x + threadIdx.x; t < 4 * PER;
         t += gridDim.x * blockDim.x) {
        int region = t >> 20;
        int i = t & (PER - 1);
        int row = i >> 8;      // 256 float4 per 1024-elem row
        int c4  = i & 255;
        const float* src = (region == 0) ? x : (region == 1) ? h : (region == 2) ? W : U;
        unsigned short* dst = (region < 2) ? Xc : Wc;
        int koff = (region & 1) << 10;
        float4 v = reinterpret_cast<const float4*>(src)[i];
        ushort4 o;
        o.x = f2bf(v.x); o.y = f2bf(v.y); o.z = f2bf(v.z); o.w = f2bf(v.w);
        *reinterpret_cast<ushort4*>(dst + (size_t)row * 2048 + koff + c4 * 4) = o;
    }
}

// ---------------------------------------------------------------------------
// Kernel 2: C[4096][4096] bf16 = A[4096][2048] * B[4096][2048]^T  (both bf16)
// m97-style: 128x128 tile, BK=64, 4 waves, global_load_lds w16, 16x16x32 MFMA
// ---------------------------------------------------------------------------
#define BM 128
#define BN 128
#define BK 64

__device__ __forceinline__ void gl16(const void* g, void* l) {
    __builtin_amdgcn_global_load_lds(
        (const __attribute__((address_space(1))) void*)g,
        (__attribute__((address_space(3))) void*)l, 16, 0, 0);
}

__global__ __launch_bounds__(256) void gemm_bt(const unsigned short* __restrict__ A,
                                               const unsigned short* __restrict__ Bw,
                                               unsigned short* __restrict__ Cg) {
    __shared__ unsigned short As[BM * BK];
    __shared__ unsigned short Bs[BN * BK];

    const int tid  = threadIdx.x;
    const int lane = tid & 63;
    const int wave = tid >> 6;
    const int wr = wave >> 1, wc = wave & 1;

    const int bm = blockIdx.x & 31;
    const int bn = blockIdx.x >> 5;
    const int brow = bm * BM, bcol = bn * BN;

    // staging: thread t loads 8 contiguous bf16 (16B); 4 issues each for A,B
    const int soff = tid * 8;
    const int srow = soff >> 6;   // 0..31
    const int scol = soff & 63;
    const unsigned short* ag = A  + (size_t)(brow + srow) * Kk + scol;
    const unsigned short* bg = Bw + (size_t)(bcol + srow) * Kk + scol;

    // MFMA fragment addressing (16x16x32 bf16):
    //   A: row = lane&15, k = (lane>>4)*8 + j   (8 contiguous bf16)
    //   B: col = lane&15, k = (lane>>4)*8 + j
    const int frow = lane & 15;
    const int fk   = (lane >> 4) * 8;

    f32x4 acc[4][4] = {};

    for (int kt = 0; kt < Kk / BK; ++kt) {
#pragma unroll
        for (int i = 0; i < 4; ++i) {
            gl16(ag + (size_t)i * 32 * Kk + kt * BK, &As[soff + i * 2048]);
            gl16(bg + (size_t)i * 32 * Kk + kt * BK, &Bs[soff + i * 2048]);
        }
        __syncthreads();  // compiler emits vmcnt(0) drain before s_barrier
#pragma unroll
        for (int ks = 0; ks < 2; ++ks) {
            bf16x8 af[4], bfr[4];
#pragma unroll
            for (int mi = 0; mi < 4; ++mi)
                af[mi] = *reinterpret_cast<const bf16x8*>(
                    &As[(wr * 64 + mi * 16 + frow) * BK + ks * 32 + fk]);
#pragma unroll
            for (int ni = 0; ni < 4; ++ni)
                bfr[ni] = *reinterpret_cast<const bf16x8*>(
                    &Bs[(wc * 64 + ni * 16 + frow) * BK + ks * 32 + fk]);
#pragma unroll
            for (int mi = 0; mi < 4; ++mi)
#pragma unroll
                for (int ni = 0; ni < 4; ++ni)
                    acc[mi][ni] = __builtin_amdgcn_mfma_f32_16x16x32_bf16(
                        af[mi], bfr[ni], acc[mi][ni], 0, 0, 0);
        }
        __syncthreads();
    }

    // epilogue: C/D layout col=lane&15, row=(lane>>4)*4+reg  [m89/m91-verified]
    const int erow0 = brow + wr * 64 + (lane >> 4) * 4;
    const int ecol0 = bcol + wc * 64 + (lane & 15);
#pragma unroll
    for (int mi = 0; mi < 4; ++mi) {
#pragma unroll
        for (int r = 0; r < 4; ++r) {
            size_t rowoff = (size_t)(erow0 + mi * 16 + r) * Nn + ecol0;
#pragma unroll
            for (int ni = 0; ni < 4; ++ni)
                Cg[rowoff + ni * 16] = f2bf(acc[mi][ni][r]);
        }
    }
}

// ---------------------------------------------------------------------------
// Kernel 3: gates + cell update.  g layout: [b][gate*1024 + h] bf16
// out[0:4M) = h_t,  out[4M:8M) = c_t   (fp32)
// ---------------------------------------------------------------------------
__global__ void lstm_elt(const unsigned short* __restrict__ g,
                         const float* __restrict__ cprev,
                         const float* __restrict__ bW, const float* __restrict__ bU,
                         float* __restrict__ out) {
    int t = blockIdx.x * blockDim.x + threadIdx.x;
    int b = t >> 10, h = t & 1023;
    const unsigned short* gb = g + ((size_t)b << 12);
    float gi = bf2f(gb[h])        + bW[h]        + bU[h];
    float gf = bf2f(gb[1024 + h]) + bW[1024 + h] + bU[1024 + h];
    float go = bf2f(gb[2048 + h]) + bW[2048 + h] + bU[2048 + h];
    float gz = bf2f(gb[3072 + h]) + bW[3072 + h] + bU[3072 + h];
    float iv = 1.f / (1.f + __expf(-gi));
    float fv = 1.f / (1.f + __expf(-gf));
    float ov = 1.f / (1.f + __expf(-go));
    float zv = tanhf(gz);
    float cv = fmaf(iv, zv, fv * cprev[t]);
    float hv = ov * tanhf(cv);
    out[t] = hv;
    out[(1 << 22) + t] = cv;
}

// ---------------------------------------------------------------------------
extern "C" void kernel_launch(void* const* d_in, const int* in_sizes, int n_in,
                              void* d_out, int out_size, void* d_ws, size_t ws_size,
                              hipStream_t stream) {
    const float* x  = (const float*)d_in[0];
    const float* h  = (const float*)d_in[1];
    const float* c  = (const float*)d_in[2];
    const float* W  = (const float*)d_in[3];
    const float* bW = (const float*)d_in[4];
    const float* U  = (const float*)d_in[5];
    const float* bU = (const float*)d_in[6];
    float* out = (float*)d_out;

    char* ws = (char*)d_ws;
    unsigned short* Xc = (unsigned short*)ws;                         // 16 MB
    unsigned short* Wc = (unsigned short*)(ws + ((size_t)16 << 20));  // 16 MB
    unsigned short* Gp = (unsigned short*)(ws + ((size_t)32 << 20));  // 32 MB

    hipLaunchKernelGGL(pack_bf16, dim3(2048), dim3(256), 0, stream, x, h, W, U, Xc, Wc);
    hipLaunchKernelGGL(gemm_bt, dim3(32 * 32), dim3(256), 0, stream, Xc, Wc, Gp);
    hipLaunchKernelGGL(lstm_elt, dim3((4096 * 1024) / 256), dim3(256), 0, stream,
                       Gp, c, bW, bU, out);
}

// Round 2
// 95.683 us; speedup vs baseline: 1.3501x; 1.3501x over previous
//
#include <hip/hip_runtime.h>
#include <math.h>

// Problem constants
#define Mm 4096   // batch B
#define Nn 4096   // 4*H (gate-major: n = g*1024 + h)
#define Kk 2048   // D + H

typedef __bf16 bf16x8 __attribute__((ext_vector_type(8)));
typedef float f32x4 __attribute__((ext_vector_type(4)));

__device__ __forceinline__ unsigned short f2bf(float f) {
    union { float f; unsigned u; } v; v.f = f;
    unsigned r = v.u + 0x7FFFu + ((v.u >> 16) & 1u);  // RNE
    return (unsigned short)(r >> 16);
}
__device__ __forceinline__ float bf2f(unsigned short s) {
    union { unsigned u; float f; } v; v.u = ((unsigned)s) << 16;
    return v.f;
}

// ---------------------------------------------------------------------------
// Kernel 1: pack x|h -> Xcat bf16 [4096][2048], W|U -> Wcat bf16 [4096][2048]
// ---------------------------------------------------------------------------
__global__ void pack_bf16(const float* __restrict__ x, const float* __restrict__ h,
                          const float* __restrict__ W, const float* __restrict__ U,
                          unsigned short* __restrict__ Xc, unsigned short* __restrict__ Wc) {
    const int PER = (4096 * 1024) / 4;  // float4 chunks per region = 2^20
    for (int t = blockIdx.x * blockDim.x + threadIdx.x; t < 4 * PER;
         t += gridDim.x * blockDim.x) {
        int region = t >> 20;
        int i = t & (PER - 1);
        int row = i >> 8;      // 256 float4 per 1024-elem row
        int c4  = i & 255;
        const float* src = (region == 0) ? x : (region == 1) ? h : (region == 2) ? W : U;
        unsigned short* dst = (region < 2) ? Xc : Wc;
        int koff = (region & 1) << 10;
        float4 v = reinterpret_cast<const float4*>(src)[i];
        ushort4 o;
        o.x = f2bf(v.x); o.y = f2bf(v.y); o.z = f2bf(v.z); o.w = f2bf(v.w);
        *reinterpret_cast<ushort4*>(dst + (size_t)row * 2048 + koff + c4 * 4) = o;
    }
}

// ---------------------------------------------------------------------------
// Kernel 2: 8-phase 256x256 GEMM (m201 template, plain HIP)
// C[4096][4096] bf16 = A[4096][2048] * B[4096][2048]^T
// 8 waves (2M x 4N), BK=64, 128 KiB LDS = 2dbuf x 2half x 128x64 x {A,B}
// LDS swizzle: byte ^= ((row&7)<<4), applied source-side for global_load_lds
// ---------------------------------------------------------------------------
__device__ __forceinline__ void gl16(const void* g, void* l) {
    __builtin_amdgcn_global_load_lds(
        (const __attribute__((address_space(1))) void*)g,
        (__attribute__((address_space(3))) void*)l, 16, 0, 0);
}

#define A_OFF(p, ah) (((p) * 2 + (ah)) * 16384)
#define B_OFF(p, hb) (65536 + ((p) * 2 + (hb)) * 16384)

__global__ __launch_bounds__(512, 2) void gemm_8ph(const unsigned short* __restrict__ A,
                                                   const unsigned short* __restrict__ Bw,
                                                   unsigned short* __restrict__ Cg) {
    extern __shared__ char lds[];
    const int tid = threadIdx.x, lane = tid & 63, wave = tid >> 6;
    const int wm = wave >> 2, wn = wave & 3;

    // bijective XCD swizzle: 256 wgs, 8 XCDs, 32 per chunk
    const int bid = blockIdx.x;
    const int swz = (bid & 7) * 32 + (bid >> 3);
    const int bm = swz & 15, bn = swz >> 4;
    const size_t Crow0 = (size_t)bm * 256, Ccol0 = (size_t)bn * 256;

    // ---- staging source addresses (inverse-swizzled global, linear LDS dest)
    // dest row within 128-row half: r = j*64 + wave*8 + (lane>>3); r&7 == lane>>3
    // dest byte-col: (lane&7)<<4 ; source byte-col = dest ^ ((r&7)<<4)
    const int srow = wave * 8 + (lane >> 3);
    const int scolswz = (((lane & 7) ^ (lane >> 3)) << 4);
    const char* aS[2][2];
    const char* bS[2][2];
#pragma unroll
    for (int ah = 0; ah < 2; ++ah)
#pragma unroll
        for (int j = 0; j < 2; ++j) {
            aS[ah][j] = (const char*)A  + (size_t)(Crow0 + ah * 128 + j * 64 + srow) * 4096 + scolswz;
            bS[ah][j] = (const char*)Bw + (size_t)(Ccol0 + ah * 128 + j * 64 + srow) * 4096 + scolswz;
        }

#define STG_A(p, ah, kb) do { \
        gl16(aS[ah][0] + (kb), lds + A_OFF(p, ah) + wave * 1024); \
        gl16(aS[ah][1] + (kb), lds + A_OFF(p, ah) + 8192 + wave * 1024); } while (0)
#define STG_B(p, hb, kb) do { \
        gl16(bS[hb][0] + (kb), lds + B_OFF(p, hb) + wave * 1024); \
        gl16(bS[hb][1] + (kb), lds + B_OFF(p, hb) + 8192 + wave * 1024); } while (0)

    // ---- LDS read addressing (swizzled): row&7 == lane&7 for all frag rows
    const int arowB = (wm * 64 + (lane & 15)) * 128;          // byte row off in A half
    const int browB = ((wn & 1) * 64 + (lane & 15)) * 128;    // byte row off in B half
    const int c0 = (((lane >> 4) << 4)) ^ ((lane & 7) << 4);        // kk=0 byte col
    const int c1 = (64 + ((lane >> 4) << 4)) ^ ((lane & 7) << 4);   // kk=1 byte col
    const int bhb = wn >> 1;

#define LDA(p, ah, mfl, ck) (*(const bf16x8*)(lds + A_OFF(p, ah) + arowB + (mfl) * 2048 + (ck)))
#define LDB(p, nf, ck)      (*(const bf16x8*)(lds + B_OFF(p, bhb) + browB + (nf) * 2048 + (ck)))

    f32x4 acc[2][4][4] = {};

#define MF8(ah, mf, ak0, ak1) \
    acc[ah][mf][0] = __builtin_amdgcn_mfma_f32_16x16x32_bf16(ak0, b00, acc[ah][mf][0], 0, 0, 0); \
    acc[ah][mf][0] = __builtin_amdgcn_mfma_f32_16x16x32_bf16(ak1, b01, acc[ah][mf][0], 0, 0, 0); \
    acc[ah][mf][1] = __builtin_amdgcn_mfma_f32_16x16x32_bf16(ak0, b10, acc[ah][mf][1], 0, 0, 0); \
    acc[ah][mf][1] = __builtin_amdgcn_mfma_f32_16x16x32_bf16(ak1, b11, acc[ah][mf][1], 0, 0, 0); \
    acc[ah][mf][2] = __builtin_amdgcn_mfma_f32_16x16x32_bf16(ak0, b20, acc[ah][mf][2], 0, 0, 0); \
    acc[ah][mf][2] = __builtin_amdgcn_mfma_f32_16x16x32_bf16(ak1, b21, acc[ah][mf][2], 0, 0, 0); \
    acc[ah][mf][3] = __builtin_amdgcn_mfma_f32_16x16x32_bf16(ak0, b30, acc[ah][mf][3], 0, 0, 0); \
    acc[ah][mf][3] = __builtin_amdgcn_mfma_f32_16x16x32_bf16(ak1, b31, acc[ah][mf][3], 0, 0, 0);

#define PH_TAIL \
    __builtin_amdgcn_s_barrier(); \
    asm volatile("s_waitcnt lgkmcnt(0)" ::: "memory"); \
    __builtin_amdgcn_s_setprio(1);

#define PH_END \
    __builtin_amdgcn_s_setprio(0); \
    __builtin_amdgcn_s_barrier();

    // K-tile group: 4 phases. Stage slots chosen so every overwrite targets a
    // slot whose last reader drained >=1 barrier earlier:
    //  phi1: stage A1(t+1) (A1(t-1) dead after phi4(t-1))
    //  phi2: stage B0(t+2) (B(t) dead after phi1)
    //  phi3: stage A0(t+2) (A0(t) dead after phi2)
    //  phi4: stage B1(t+2); vmcnt(6) -> everything up through A1(t+1) landed
#define GROUP(p, kbA1, kbT2) \
    { \
        bf16x8 b00 = LDB(p, 0, c0), b01 = LDB(p, 0, c1), b10 = LDB(p, 1, c0), b11 = LDB(p, 1, c1); \
        bf16x8 b20 = LDB(p, 2, c0), b21 = LDB(p, 2, c1), b30 = LDB(p, 3, c0), b31 = LDB(p, 3, c1); \
        { /* phi1 */ \
            bf16x8 a00 = LDA(p, 0, 0, c0), a01 = LDA(p, 0, 0, c1); \
            bf16x8 a10 = LDA(p, 0, 1, c0), a11 = LDA(p, 0, 1, c1); \
            STG_A((p) ^ 1, 1, kbA1); \
            PH_TAIL MF8(0, 0, a00, a01) MF8(0, 1, a10, a11) PH_END \
        } \
        { /* phi2 */ \
            bf16x8 a00 = LDA(p, 0, 2, c0), a01 = LDA(p, 0, 2, c1); \
            bf16x8 a10 = LDA(p, 0, 3, c0), a11 = LDA(p, 0, 3, c1); \
            STG_B(p, 0, kbT2); \
            PH_TAIL MF8(0, 2, a00, a01) MF8(0, 3, a10, a11) PH_END \
        } \
        { /* phi3 */ \
            bf16x8 a00 = LDA(p, 1, 0, c0), a01 = LDA(p, 1, 0, c1); \
            bf16x8 a10 = LDA(p, 1, 1, c0), a11 = LDA(p, 1, 1, c1); \
            STG_A(p, 0, kbT2); \
            PH_TAIL MF8(1, 0, a00, a01) MF8(1, 1, a10, a11) PH_END \
        } \
        { /* phi4 */ \
            bf16x8 a00 = LDA(p, 1, 2, c0), a01 = LDA(p, 1, 2, c1); \
            bf16x8 a10 = LDA(p, 1, 3, c0), a11 = LDA(p, 1, 3, c1); \
            STG_B(p, 1, kbT2); \
            __builtin_amdgcn_s_barrier(); \
            asm volatile("s_waitcnt lgkmcnt(0)" ::: "memory"); \
            __builtin_amdgcn_s_setprio(1); \
            MF8(1, 2, a00, a01) MF8(1, 3, a10, a11) \
            __builtin_amdgcn_s_setprio(0); \
            asm volatile("s_waitcnt vmcnt(6)" ::: "memory"); \
            __builtin_amdgcn_s_barrier(); \
        } \
    }

    // ---- prologue: 7 half-tiles in steady-state virtual order
    STG_B(0, 0, 0);            // B0(0)
    STG_A(0, 0, 0);            // A0(0)
    STG_B(0, 1, 0);            // B1(0)
    STG_A(0, 1, 0);            // A1(0)
    STG_B(1, 0, 128);          // B0(1)
    STG_A(1, 0, 128);          // A0(1)
    STG_B(1, 1, 128);          // B1(1)
    asm volatile("s_waitcnt vmcnt(6)" ::: "memory");
    __builtin_amdgcn_s_barrier();

    // ---- main loop: 16 iterations x 2 K-tiles (K = 2048 = 32 x 64)
    for (int it = 0; it < 16; ++it) {
        const int t0 = 2 * it;
        const size_t kA1_0 = (size_t)(t0 + 1) * 128;                       // A1(t0+1), t0+1 <= 31
        const size_t kT2_0 = (t0 + 2 <= 31) ? (size_t)(t0 + 2) * 128 : 0;  // t0+2 stages
        const size_t kA1_1 = kT2_0;                                        // A1(t0+2)
        const size_t kT2_1 = (t0 + 3 <= 31) ? (size_t)(t0 + 3) * 128 : 0;  // t0+3 stages
        GROUP(0, kA1_0, kT2_0)
        GROUP(1, kA1_1, kT2_1)
    }

    // ---- epilogue: C/D layout col=lane&15, row=(lane>>4)*4+reg
    const int er0 = (lane >> 4) * 4;
    const int ec = lane & 15;
#pragma unroll
    for (int ah = 0; ah < 2; ++ah)
#pragma unroll
        for (int mf = 0; mf < 4; ++mf)
#pragma unroll
            for (int r = 0; r < 4; ++r) {
                const size_t row = Crow0 + ah * 128 + wm * 64 + mf * 16 + er0 + r;
#pragma unroll
                for (int nf = 0; nf < 4; ++nf) {
                    const size_t col = Ccol0 + wn * 64 + nf * 16 + ec;
                    Cg[row * 4096 + col] = f2bf(acc[ah][mf][nf][r]);
                }
            }
}

// ---------------------------------------------------------------------------
// Kernel 3: gates + cell update.  g layout: [b][gate*1024 + h] bf16
// out[0:4M) = h_t,  out[4M:8M) = c_t   (fp32)
// ---------------------------------------------------------------------------
__global__ void lstm_elt(const unsigned short* __restrict__ g,
                         const float* __restrict__ cprev,
                         const float* __restrict__ bW, const float* __restrict__ bU,
                         float* __restrict__ out) {
    int t = blockIdx.x * blockDim.x + threadIdx.x;
    int b = t >> 10, h = t & 1023;
    const unsigned short* gb = g + ((size_t)b << 12);
    float gi = bf2f(gb[h])        + bW[h]        + bU[h];
    float gf = bf2f(gb[1024 + h]) + bW[1024 + h] + bU[1024 + h];
    float go = bf2f(gb[2048 + h]) + bW[2048 + h] + bU[2048 + h];
    float gz = bf2f(gb[3072 + h]) + bW[3072 + h] + bU[3072 + h];
    float iv = 1.f / (1.f + __expf(-gi));
    float fv = 1.f / (1.f + __expf(-gf));
    float ov = 1.f / (1.f + __expf(-go));
    float zv = tanhf(gz);
    float cv = fmaf(iv, zv, fv * cprev[t]);
    float hv = ov * tanhf(cv);
    out[t] = hv;
    out[(1 << 22) + t] = cv;
}

// ---------------------------------------------------------------------------
extern "C" void kernel_launch(void* const* d_in, const int* in_sizes, int n_in,
                              void* d_out, int out_size, void* d_ws, size_t ws_size,
                              hipStream_t stream) {
    const float* x  = (const float*)d_in[0];
    const float* h  = (const float*)d_in[1];
    const float* c  = (const float*)d_in[2];
    const float* W  = (const float*)d_in[3];
    const float* bW = (const float*)d_in[4];
    const float* U  = (const float*)d_in[5];
    const float* bU = (const float*)d_in[6];
    float* out = (float*)d_out;

    char* ws = (char*)d_ws;
    unsigned short* Xc = (unsigned short*)ws;                         // 16 MB
    unsigned short* Wc = (unsigned short*)(ws + ((size_t)16 << 20));  // 16 MB
    unsigned short* Gp = (unsigned short*)(ws + ((size_t)32 << 20));  // 32 MB

    // allow 128 KiB dynamic LDS (idempotent; host-side, capture-safe)
    (void)hipFuncSetAttribute((const void*)gemm_8ph,
                              hipFuncAttributeMaxDynamicSharedMemorySize, 131072);

    hipLaunchKernelGGL(pack_bf16, dim3(2048), dim3(256), 0, stream, x, h, W, U, Xc, Wc);
    hipLaunchKernelGGL(gemm_8ph, dim3(256), dim3(512), 131072, stream, Xc, Wc, Gp);
    hipLaunchKernelGGL(lstm_elt, dim3((4096 * 1024) / 256), dim3(256), 0, stream,
                       Gp, c, bW, bU, out);
}

// Round 3
// 87.677 us; speedup vs baseline: 1.4733x; 1.0913x over previous
//
#include <hip/hip_runtime.h>
#include <math.h>

// Problem constants
#define Mm 4096   // batch B
#define Nn 4096   // 4*H, gate-interleaved: n = h*4 + g
#define Kk 2048   // D + H

typedef __bf16 bf16x8 __attribute__((ext_vector_type(8)));
typedef float f32x4 __attribute__((ext_vector_type(4)));

__device__ __forceinline__ unsigned short f2bf(float f) {
    union { float f; unsigned u; } v; v.f = f;
    unsigned r = v.u + 0x7FFFu + ((v.u >> 16) & 1u);  // RNE
    return (unsigned short)(r >> 16);
}

// ---------------------------------------------------------------------------
// Kernel 1: pack x|h -> Xcat bf16 [4096][2048]
//           W|U -> Wcat bf16 [4096][2048] with row n = h*4+g (gate-interleave)
//           bsum[n] = bW + bU in the same interleaved order
// ---------------------------------------------------------------------------
__global__ void pack_bf16(const float* __restrict__ x, const float* __restrict__ h,
                          const float* __restrict__ W, const float* __restrict__ U,
                          const float* __restrict__ bW, const float* __restrict__ bU,
                          unsigned short* __restrict__ Xc, unsigned short* __restrict__ Wc,
                          float* __restrict__ bsum) {
    if (blockIdx.x == 0) {
#pragma unroll
        for (int j = 0; j < 16; ++j) {
            int n = threadIdx.x * 16 + j;
            int hh = n >> 2, g = n & 3;
            bsum[n] = bW[g * 1024 + hh] + bU[g * 1024 + hh];
        }
    }
    const int PER = (4096 * 1024) / 4;  // float4 chunks per region = 2^20
    for (int t = blockIdx.x * blockDim.x + threadIdx.x; t < 4 * PER;
         t += gridDim.x * blockDim.x) {
        int region = t >> 20;
        int i = t & (PER - 1);
        int row = i >> 8;      // 256 float4 per 1024-elem row
        int c4  = i & 255;
        const float* src = (region == 0) ? x : (region == 1) ? h : (region == 2) ? W : U;
        float4 v = reinterpret_cast<const float4*>(src)[i];
        ushort4 o;
        o.x = f2bf(v.x); o.y = f2bf(v.y); o.z = f2bf(v.z); o.w = f2bf(v.w);
        if (region < 2) {
            *reinterpret_cast<ushort4*>(Xc + (size_t)row * 2048 + (region << 10) + c4 * 4) = o;
        } else {
            int g = row >> 10, hh = row & 1023;
            *reinterpret_cast<ushort4*>(Wc + (size_t)(hh * 4 + g) * 2048 + ((region & 1) << 10) + c4 * 4) = o;
        }
    }
}

// ---------------------------------------------------------------------------
// Kernel 2: 8-phase 256x256 GEMM + fused LSTM epilogue
// C[4096][4096] = Xc[4096][2048] * Wc[4096][2048]^T  (bf16, fp32 acc)
// then per (b,h): gates at cols 4h..4h+3 -> c_t, h_t written directly.
// ---------------------------------------------------------------------------
__device__ __forceinline__ void gl16(const void* g, void* l) {
    __builtin_amdgcn_global_load_lds(
        (const __attribute__((address_space(1))) void*)g,
        (__attribute__((address_space(3))) void*)l, 16, 0, 0);
}

#define A_OFF(p, ah) (((p) * 2 + (ah)) * 16384)
#define B_OFF(p, hb) (65536 + ((p) * 2 + (hb)) * 16384)

__global__ __launch_bounds__(512, 2) void gemm_8ph(const unsigned short* __restrict__ A,
                                                   const unsigned short* __restrict__ Bw,
                                                   const float* __restrict__ bsum,
                                                   const float* __restrict__ cprev,
                                                   float* __restrict__ out) {
    extern __shared__ char lds[];
    const int tid = threadIdx.x, lane = tid & 63, wave = tid >> 6;
    const int wm = wave >> 2, wn = wave & 3;

    // bijective XCD swizzle: 256 wgs, 8 XCDs, 32 per chunk
    const int bid = blockIdx.x;
    const int swz = (bid & 7) * 32 + (bid >> 3);
    const int bm = swz & 15, bn = swz >> 4;
    const size_t Crow0 = (size_t)bm * 256, Ccol0 = (size_t)bn * 256;

    // ---- staging source addresses (inverse-swizzled global, linear LDS dest)
    const int srow = wave * 8 + (lane >> 3);
    const int scolswz = (((lane & 7) ^ (lane >> 3)) << 4);
    const char* aS[2][2];
    const char* bS[2][2];
#pragma unroll
    for (int ah = 0; ah < 2; ++ah)
#pragma unroll
        for (int j = 0; j < 2; ++j) {
            aS[ah][j] = (const char*)A  + (size_t)(Crow0 + ah * 128 + j * 64 + srow) * 4096 + scolswz;
            bS[ah][j] = (const char*)Bw + (size_t)(Ccol0 + ah * 128 + j * 64 + srow) * 4096 + scolswz;
        }

#define STG_A(p, ah, kb) do { \
        gl16(aS[ah][0] + (kb), lds + A_OFF(p, ah) + wave * 1024); \
        gl16(aS[ah][1] + (kb), lds + A_OFF(p, ah) + 8192 + wave * 1024); } while (0)
#define STG_B(p, hb, kb) do { \
        gl16(bS[hb][0] + (kb), lds + B_OFF(p, hb) + wave * 1024); \
        gl16(bS[hb][1] + (kb), lds + B_OFF(p, hb) + 8192 + wave * 1024); } while (0)

    // ---- LDS read addressing (swizzled)
    const int arowB = (wm * 64 + (lane & 15)) * 128;
    const int browB = ((wn & 1) * 64 + (lane & 15)) * 128;
    const int c0 = (((lane >> 4) << 4)) ^ ((lane & 7) << 4);
    const int c1 = (64 + ((lane >> 4) << 4)) ^ ((lane & 7) << 4);
    const int bhb = wn >> 1;

#define LDA(p, ah, mfl, ck) (*(const bf16x8*)(lds + A_OFF(p, ah) + arowB + (mfl) * 2048 + (ck)))
#define LDB(p, nf, ck)      (*(const bf16x8*)(lds + B_OFF(p, bhb) + browB + (nf) * 2048 + (ck)))

    f32x4 acc[2][4][4] = {};

#define MF8(ah, mf, ak0, ak1) \
    acc[ah][mf][0] = __builtin_amdgcn_mfma_f32_16x16x32_bf16(ak0, b00, acc[ah][mf][0], 0, 0, 0); \
    acc[ah][mf][0] = __builtin_amdgcn_mfma_f32_16x16x32_bf16(ak1, b01, acc[ah][mf][0], 0, 0, 0); \
    acc[ah][mf][1] = __builtin_amdgcn_mfma_f32_16x16x32_bf16(ak0, b10, acc[ah][mf][1], 0, 0, 0); \
    acc[ah][mf][1] = __builtin_amdgcn_mfma_f32_16x16x32_bf16(ak1, b11, acc[ah][mf][1], 0, 0, 0); \
    acc[ah][mf][2] = __builtin_amdgcn_mfma_f32_16x16x32_bf16(ak0, b20, acc[ah][mf][2], 0, 0, 0); \
    acc[ah][mf][2] = __builtin_amdgcn_mfma_f32_16x16x32_bf16(ak1, b21, acc[ah][mf][2], 0, 0, 0); \
    acc[ah][mf][3] = __builtin_amdgcn_mfma_f32_16x16x32_bf16(ak0, b30, acc[ah][mf][3], 0, 0, 0); \
    acc[ah][mf][3] = __builtin_amdgcn_mfma_f32_16x16x32_bf16(ak1, b31, acc[ah][mf][3], 0, 0, 0);

#define PH_TAIL \
    __builtin_amdgcn_s_barrier(); \
    asm volatile("s_waitcnt lgkmcnt(0)" ::: "memory"); \
    __builtin_amdgcn_s_setprio(1);

#define PH_END \
    __builtin_amdgcn_s_setprio(0); \
    __builtin_amdgcn_s_barrier();

#define GROUP(p, kbA1, kbT2) \
    { \
        bf16x8 b00 = LDB(p, 0, c0), b01 = LDB(p, 0, c1), b10 = LDB(p, 1, c0), b11 = LDB(p, 1, c1); \
        bf16x8 b20 = LDB(p, 2, c0), b21 = LDB(p, 2, c1), b30 = LDB(p, 3, c0), b31 = LDB(p, 3, c1); \
        { /* phi1 */ \
            bf16x8 a00 = LDA(p, 0, 0, c0), a01 = LDA(p, 0, 0, c1); \
            bf16x8 a10 = LDA(p, 0, 1, c0), a11 = LDA(p, 0, 1, c1); \
            STG_A((p) ^ 1, 1, kbA1); \
            PH_TAIL MF8(0, 0, a00, a01) MF8(0, 1, a10, a11) PH_END \
        } \
        { /* phi2 */ \
            bf16x8 a00 = LDA(p, 0, 2, c0), a01 = LDA(p, 0, 2, c1); \
            bf16x8 a10 = LDA(p, 0, 3, c0), a11 = LDA(p, 0, 3, c1); \
            STG_B(p, 0, kbT2); \
            PH_TAIL MF8(0, 2, a00, a01) MF8(0, 3, a10, a11) PH_END \
        } \
        { /* phi3 */ \
            bf16x8 a00 = LDA(p, 1, 0, c0), a01 = LDA(p, 1, 0, c1); \
            bf16x8 a10 = LDA(p, 1, 1, c0), a11 = LDA(p, 1, 1, c1); \
            STG_A(p, 0, kbT2); \
            PH_TAIL MF8(1, 0, a00, a01) MF8(1, 1, a10, a11) PH_END \
        } \
        { /* phi4 */ \
            bf16x8 a00 = LDA(p, 1, 2, c0), a01 = LDA(p, 1, 2, c1); \
            bf16x8 a10 = LDA(p, 1, 3, c0), a11 = LDA(p, 1, 3, c1); \
            STG_B(p, 1, kbT2); \
            __builtin_amdgcn_s_barrier(); \
            asm volatile("s_waitcnt lgkmcnt(0)" ::: "memory"); \
            __builtin_amdgcn_s_setprio(1); \
            MF8(1, 2, a00, a01) MF8(1, 3, a10, a11) \
            __builtin_amdgcn_s_setprio(0); \
            asm volatile("s_waitcnt vmcnt(6)" ::: "memory"); \
            __builtin_amdgcn_s_barrier(); \
        } \
    }

    // ---- prologue: 7 half-tiles in steady-state virtual order
    STG_B(0, 0, 0);
    STG_A(0, 0, 0);
    STG_B(0, 1, 0);
    STG_A(0, 1, 0);
    STG_B(1, 0, 128);
    STG_A(1, 0, 128);
    STG_B(1, 1, 128);
    asm volatile("s_waitcnt vmcnt(6)" ::: "memory");
    __builtin_amdgcn_s_barrier();

    // ---- main loop: 16 iterations x 2 K-tiles (K = 2048 = 32 x 64)
    for (int it = 0; it < 16; ++it) {
        const int t0 = 2 * it;
        const size_t kA1_0 = (size_t)(t0 + 1) * 128;
        const size_t kT2_0 = (t0 + 2 <= 31) ? (size_t)(t0 + 2) * 128 : 0;
        const size_t kA1_1 = kT2_0;
        const size_t kT2_1 = (t0 + 3 <= 31) ? (size_t)(t0 + 3) * 128 : 0;
        GROUP(0, kA1_0, kT2_0)
        GROUP(1, kA1_1, kT2_1)
    }

    // ---- fused LSTM epilogue ------------------------------------------------
    // Drain stray prefetches + all LDS reads, then reuse LDS as C staging.
    __syncthreads();

    const int Hbase = (int)(Ccol0 >> 2);   // 64 h-values per block
    const int ec = lane & 15, er0 = (lane >> 4) * 4;

#pragma unroll
    for (int ah = 0; ah < 2; ++ah) {
        if (ah) __syncthreads();  // all reads of previous half done
        // dump acc[ah] -> LDS [128 rows][256 cols] fp32, XOR (row&4)<<4
#pragma unroll
        for (int mf = 0; mf < 4; ++mf)
#pragma unroll
            for (int r = 0; r < 4; ++r) {
                const int lrow = wm * 64 + mf * 16 + er0 + r;
                const int sw = (lrow & 4) << 4;
#pragma unroll
                for (int nf = 0; nf < 4; ++nf) {
                    const int col = wn * 64 + nf * 16 + ec;
                    *(float*)(lds + lrow * 1024 + ((col * 4) ^ sw)) = acc[ah][mf][nf][r];
                }
            }
        __syncthreads();
        // each wave: one row per iter, h = lane
#pragma unroll
        for (int i = 0; i < 16; ++i) {
            const int lrow = i * 8 + wave;
            const int sw = (lrow & 4) << 4;
            f32x4 g4 = *(const f32x4*)(lds + lrow * 1024 + ((lane * 16) ^ sw));
            f32x4 bs = *(const f32x4*)(bsum + (size_t)(Hbase + lane) * 4);
            const size_t bg = Crow0 + ah * 128 + lrow;
            const size_t oidx = bg * 1024 + Hbase + lane;
            float cp = cprev[oidx];
            float gi = g4[0] + bs[0], gf = g4[1] + bs[1];
            float go = g4[2] + bs[2], gz = g4[3] + bs[3];
            float iv = 1.f / (1.f + __expf(-gi));
            float fv = 1.f / (1.f + __expf(-gf));
            float ov = 1.f / (1.f + __expf(-go));
            float zv = tanhf(gz);
            float cc = fmaf(iv, zv, fv * cp);
            float hv = ov * tanhf(cc);
            out[oidx] = hv;
            out[(1 << 22) + oidx] = cc;
        }
    }
}

// ---------------------------------------------------------------------------
extern "C" void kernel_launch(void* const* d_in, const int* in_sizes, int n_in,
                              void* d_out, int out_size, void* d_ws, size_t ws_size,
                              hipStream_t stream) {
    const float* x  = (const float*)d_in[0];
    const float* h  = (const float*)d_in[1];
    const float* c  = (const float*)d_in[2];
    const float* W  = (const float*)d_in[3];
    const float* bW = (const float*)d_in[4];
    const float* U  = (const float*)d_in[5];
    const float* bU = (const float*)d_in[6];
    float* out = (float*)d_out;

    char* ws = (char*)d_ws;
    unsigned short* Xc = (unsigned short*)ws;                         // 16 MB
    unsigned short* Wc = (unsigned short*)(ws + ((size_t)16 << 20));  // 16 MB
    float* bsum = (float*)(ws + ((size_t)32 << 20));                  // 16 KB

    (void)hipFuncSetAttribute((const void*)gemm_8ph,
                              hipFuncAttributeMaxDynamicSharedMemorySize, 131072);

    hipLaunchKernelGGL(pack_bf16, dim3(2048), dim3(256), 0, stream,
                       x, h, W, U, bW, bU, Xc, Wc, bsum);
    hipLaunchKernelGGL(gemm_8ph, dim3(256), dim3(512), 131072, stream,
                       Xc, Wc, bsum, c, out);
}